// Round 3
// baseline (541.498 us; speedup 1.0000x reference)
//
#include <hip/hip_runtime.h>
#include <hip/hip_bf16.h>

typedef unsigned short u16;
typedef unsigned int u32;

#define M_DIM 8192   // B*S = 4*2048
#define K_DIM 4096   // I
#define N_DIM 4096   // O
#define GROUPS 64    // I / GROUP_SIZE

typedef __bf16 bf16x8 __attribute__((ext_vector_type(8)));
typedef float floatx4 __attribute__((ext_vector_type(4)));

__device__ __forceinline__ u16 f2bf(float f) {
  u32 u = __builtin_bit_cast(u32, f);
  u32 r = u + 0x7fffu + ((u >> 16) & 1u);   // RNE, inputs are finite
  return (u16)(r >> 16);
}

__device__ __forceinline__ void gload_lds16(const void* g, void* l) {
  __builtin_amdgcn_global_load_lds(
      (const __attribute__((address_space(1))) void*)g,
      (__attribute__((address_space(3))) void*)l, 16, 0, 0);
}

// ---------------- kernel 1: xb[m][p] = bf16(x[m][p]*cs[p]) ----------------
__global__ __launch_bounds__(256) void prep_x(
    const float* __restrict__ x, const float* __restrict__ cs,
    u16* __restrict__ xb) {
  const size_t total = (size_t)M_DIM * K_DIM / 4;   // float4 count
  const size_t stride = (size_t)gridDim.x * 256;
  for (size_t idx = (size_t)blockIdx.x * 256 + threadIdx.x; idx < total;
       idx += stride) {
    float4 v = ((const float4*)x)[idx];
    float4 c = ((const float4*)cs)[idx & (K_DIM / 4 - 1)];
    u32 lo = (u32)f2bf(v.x * c.x) | ((u32)f2bf(v.y * c.y) << 16);
    u32 hi = (u32)f2bf(v.z * c.z) | ((u32)f2bf(v.w * c.w) << 16);
    ((uint2*)xb)[idx] = make_uint2(lo, hi);
  }
}

// ------- kernel 2: W2[o][perm[j]] = bf16(nib_j(qw[o])*scale + zero) -------
__global__ __launch_bounds__(256) void prep_w2(
    const u32* __restrict__ qw, const int* __restrict__ perm,
    const float* __restrict__ scales, const float* __restrict__ zeros,
    u16* __restrict__ wb) {
  __shared__ u16 rowbuf[K_DIM];   // 8 KB
  const int o = blockIdx.x;
  const u32* qrow = qw + (size_t)o * (K_DIM / 8);
#pragma unroll
  for (int t = threadIdx.x; t < K_DIM / 8; t += 256) {
    u32 q = qrow[t];
    int j0 = t * 8;
    int g = t >> 3;   // 8 words per group of 64
    float s = scales[o * GROUPS + g];
    float z = zeros[o * GROUPS + g];
#pragma unroll
    for (int n = 0; n < 8; ++n) {
      float v = (float)((q >> (4 * n)) & 15u) * s + z;
      rowbuf[perm[j0 + n]] = f2bf(v);
    }
  }
  __syncthreads();
  uint4* dst = (uint4*)(wb + (size_t)o * K_DIM);
  const uint4* src = (const uint4*)rowbuf;
  for (int t = threadIdx.x; t < K_DIM / 8; t += 256) dst[t] = src[t];
}

// ---------------- kernel 3: out = Xb @ Wb^T + bias ----------------
// BK=64: LDS row = 128 B = 8 x 16B chunks. Physical chunk slot p of row r
// holds global chunk p ^ ((r>>1)&7) (swizzle applied on the global source
// address; LDS dest stays uniform+lane*16 for global_load_lds). Reads
// un-swizzle with slot = (t*4+q) ^ ((lr>>1)&7). 64 barrier iterations
// instead of 128; 32 MFMAs per wave per barrier.
__global__ __launch_bounds__(256) void gemm_bt(
    const u16* __restrict__ A, const u16* __restrict__ B,
    const float* __restrict__ bias, float* __restrict__ out) {
  __shared__ __align__(16) u16 As[128 * 64];   // 16 KB
  __shared__ __align__(16) u16 Bs[128 * 64];   // 16 KB
  const int tid = threadIdx.x;
  const int lane = tid & 63;
  const int wave = tid >> 6;
  const int wm = wave >> 1, wn = wave & 1;
  const int q = lane >> 4, lr = lane & 15;
  const int rsw = (lr >> 1) & 7;   // row-derived swizzle bits for reads
  const int blockN = blockIdx.x * 128;
  const int blockM = blockIdx.y * 128;

  floatx4 acc[4][4];
#pragma unroll
  for (int i = 0; i < 4; ++i)
#pragma unroll
    for (int j = 0; j < 4; ++j) acc[i][j] = (floatx4)0.0f;

  const char* Abase = (const char*)(A + (size_t)blockM * K_DIM);
  const char* Bbase = (const char*)(B + (size_t)blockN * K_DIM);
  const size_t rowb = (size_t)K_DIM * 2;

  // staging: 1024 chunks per matrix, 4 per thread; idx = j*256 + tid
  int sr[4], sc[4];
#pragma unroll
  for (int j = 0; j < 4; ++j) {
    const int idx = j * 256 + tid;
    sr[j] = idx >> 3;                          // row 0..127
    sc[j] = (idx & 7) ^ ((sr[j] >> 1) & 7);    // global chunk to fetch
  }

  for (int kt = 0; kt < K_DIM / 64; ++kt) {
    const size_t koff = (size_t)kt * 128;
#pragma unroll
    for (int j = 0; j < 4; ++j)
      gload_lds16(Abase + (size_t)sr[j] * rowb + koff + sc[j] * 16,
                  &As[(j * 256 + tid) * 8]);
#pragma unroll
    for (int j = 0; j < 4; ++j)
      gload_lds16(Bbase + (size_t)sr[j] * rowb + koff + sc[j] * 16,
                  &Bs[(j * 256 + tid) * 8]);
    __syncthreads();

#pragma unroll
    for (int t = 0; t < 2; ++t) {
      const int slot = (t * 4 + q) ^ rsw;   // physical 16B chunk to read
      bf16x8 af[4], bfr[4];
#pragma unroll
      for (int mi = 0; mi < 4; ++mi)
        af[mi] = *(const bf16x8*)&As[(wm * 64 + mi * 16 + lr) * 64 + slot * 8];
#pragma unroll
      for (int ni = 0; ni < 4; ++ni)
        bfr[ni] = *(const bf16x8*)&Bs[(wn * 64 + ni * 16 + lr) * 64 + slot * 8];
#pragma unroll
      for (int mi = 0; mi < 4; ++mi)
#pragma unroll
        for (int ni = 0; ni < 4; ++ni)
          acc[mi][ni] = __builtin_amdgcn_mfma_f32_16x16x32_bf16(
              af[mi], bfr[ni], acc[mi][ni], 0, 0, 0);
    }
    __syncthreads();
  }

  // epilogue: C/D layout col = lane&15, row = quad*4 + reg
#pragma unroll
  for (int ni = 0; ni < 4; ++ni) {
    const int col = blockN + wn * 64 + ni * 16 + lr;
    const float bv = bias[col];
#pragma unroll
    for (int mi = 0; mi < 4; ++mi) {
      const int row0 = blockM + wm * 64 + mi * 16 + q * 4;
#pragma unroll
      for (int r = 0; r < 4; ++r)
        out[(size_t)(row0 + r) * N_DIM + col] = acc[mi][ni][r] + bv;
    }
  }
}

extern "C" void kernel_launch(void* const* d_in, const int* in_sizes, int n_in,
                              void* d_out, int out_size, void* d_ws, size_t ws_size,
                              hipStream_t stream) {
  const float* x      = (const float*)d_in[0];
  const float* cs     = (const float*)d_in[1];
  const u32*   qw     = (const u32*)d_in[2];
  const int*   perm   = (const int*)d_in[3];
  const float* scales = (const float*)d_in[4];
  const float* zeros  = (const float*)d_in[5];
  const float* bias   = (const float*)d_in[6];
  float* out = (float*)d_out;

  u16* xb = (u16*)d_ws;                          // 64 MiB: M*K bf16
  u16* wb = xb + (size_t)M_DIM * K_DIM;          // 32 MiB: N*K bf16 (permuted cols)

  hipLaunchKernelGGL(prep_x, dim3(8192), dim3(256), 0, stream, x, cs, xb);
  hipLaunchKernelGGL(prep_w2, dim3(N_DIM), dim3(256), 0, stream,
                     qw, perm, scales, zeros, wb);
  hipLaunchKernelGGL(gemm_bt, dim3(N_DIM / 128, M_DIM / 128), dim3(256), 0,
                     stream, xb, wb, bias, out);
}

// Round 4
// 409.706 us; speedup vs baseline: 1.3217x; 1.3217x over previous
//
#include <hip/hip_runtime.h>
#include <hip/hip_bf16.h>

typedef unsigned short u16;
typedef unsigned int u32;
typedef unsigned char u8;

#define M_DIM 8192   // B*S = 4*2048
#define K_DIM 4096   // I
#define N_DIM 4096   // O
#define GROUPS 64    // I / GROUP_SIZE

typedef int intx4 __attribute__((ext_vector_type(4)));

__device__ __forceinline__ void gload_lds16(const void* g, void* l) {
  __builtin_amdgcn_global_load_lds(
      (const __attribute__((address_space(1))) void*)g,
      (__attribute__((address_space(3))) void*)l, 16, 0, 0);
}

__device__ __forceinline__ float block_absmax(float amax, float* red) {
  // wave butterfly then cross-wave via LDS (4 waves, 256 threads)
#pragma unroll
  for (int off = 32; off; off >>= 1)
    amax = fmaxf(amax, __shfl_xor(amax, off, 64));
  const int wave = threadIdx.x >> 6;
  if ((threadIdx.x & 63) == 0) red[wave] = amax;
  __syncthreads();
  return fmaxf(fmaxf(red[0], red[1]), fmaxf(red[2], red[3]));
}

__device__ __forceinline__ u32 pack4(const float* v, float inv) {
  u32 r = 0;
#pragma unroll
  for (int i = 0; i < 4; ++i) {
    int q = (int)__builtin_rintf(v[i] * inv);
    q = q > 127 ? 127 : (q < -127 ? -127 : q);
    r |= ((u32)(u8)(char)q) << (8 * i);
  }
  return r;
}

// ---- kernel 1: per-row symmetric int8 quant of x*cs; sx[m]=absmax/127 ----
__global__ __launch_bounds__(256) void prep_x(
    const float* __restrict__ x, const float* __restrict__ cs,
    u8* __restrict__ xq, float* __restrict__ sx) {
  __shared__ float red[4];
  const size_t m = blockIdx.x;
  const float* xr = x + m * K_DIM;
  const int base = threadIdx.x * 16;   // 16 consecutive elems per thread
  float v[16];
  float amax = 0.f;
#pragma unroll
  for (int j = 0; j < 4; ++j) {
    float4 xv = *(const float4*)(xr + base + j * 4);
    float4 cv = *(const float4*)(cs + base + j * 4);
    v[j * 4 + 0] = xv.x * cv.x;
    v[j * 4 + 1] = xv.y * cv.y;
    v[j * 4 + 2] = xv.z * cv.z;
    v[j * 4 + 3] = xv.w * cv.w;
#pragma unroll
    for (int i = 0; i < 4; ++i) amax = fmaxf(amax, fabsf(v[j * 4 + i]));
  }
  amax = block_absmax(amax, red);
  amax = fmaxf(amax, 1e-20f);
  const float inv = 127.0f / amax;
  uint4 p;
  p.x = pack4(v + 0, inv);
  p.y = pack4(v + 4, inv);
  p.z = pack4(v + 8, inv);
  p.w = pack4(v + 12, inv);
  *(uint4*)(xq + m * K_DIM + base) = p;
  if (threadIdx.x == 0) sx[m] = amax * (1.0f / 127.0f);
}

// ---- kernel 2: dequant+permute one weight row, int8 quant; sw[o] ----
// W2[o][perm[j]] = nib_j(qw[o])*scale + zero, scattered via 16 KB LDS.
__global__ __launch_bounds__(256) void prep_w(
    const u32* __restrict__ qw, const int* __restrict__ perm,
    const float* __restrict__ scales, const float* __restrict__ zeros,
    u8* __restrict__ wq, float* __restrict__ sw) {
  __shared__ float rowbuf[K_DIM];   // 16 KB
  __shared__ float red[4];
  const int o = blockIdx.x;
  const u32* qrow = qw + (size_t)o * (K_DIM / 8);
  float amax = 0.f;
#pragma unroll
  for (int it = 0; it < 2; ++it) {
    int t = it * 256 + threadIdx.x;   // word index 0..511
    u32 q = qrow[t];
    int g = t >> 3;
    float s = scales[o * GROUPS + g];
    float z = zeros[o * GROUPS + g];
#pragma unroll
    for (int n = 0; n < 8; ++n) {
      float v = (float)((q >> (4 * n)) & 15u) * s + z;
      amax = fmaxf(amax, fabsf(v));
      rowbuf[perm[t * 8 + n]] = v;
    }
  }
  __syncthreads();   // rowbuf complete
  amax = block_absmax(amax, red);   // contains its own __syncthreads
  amax = fmaxf(amax, 1e-20f);
  const float inv = 127.0f / amax;
  const int base = threadIdx.x * 16;
  uint4 p;
  p.x = pack4(rowbuf + base + 0, inv);
  p.y = pack4(rowbuf + base + 4, inv);
  p.z = pack4(rowbuf + base + 8, inv);
  p.w = pack4(rowbuf + base + 12, inv);
  *(uint4*)(wq + (size_t)o * K_DIM + base) = p;
  if (threadIdx.x == 0) sw[o] = amax * (1.0f / 127.0f);
}

// ---- kernel 3: out[m][o] = sx[m]*sw[o]*(Xq @ Wq^T)[m][o] + bias[o] ----
// i8 MFMA 16x16x64: one instruction covers K=64 per 16B/lane fragment —
// 2x the K per staged byte vs bf16. LDS row = 64 B = 4 x 16B chunks,
// XOR-swizzled exactly like the verified-conflict-free R2 scheme:
// physical slot p of row r holds global chunk p ^ ((r>>1)&3); reads
// un-swizzle with slot = q ^ ((lr>>1)&3).
__global__ __launch_bounds__(256) void gemm_i8(
    const u8* __restrict__ A, const u8* __restrict__ B,
    const float* __restrict__ sx, const float* __restrict__ sw,
    const float* __restrict__ bias, float* __restrict__ out) {
  __shared__ __align__(16) u8 As[128 * 64];   // 8 KB
  __shared__ __align__(16) u8 Bs[128 * 64];   // 8 KB
  const int tid = threadIdx.x;
  const int lane = tid & 63;
  const int wave = tid >> 6;
  const int wm = wave >> 1, wn = wave & 1;
  const int q = lane >> 4, lr = lane & 15;
  const int qs = q ^ ((lr >> 1) & 3);   // physical 16B slot for frag reads
  const int blockN = blockIdx.x * 128;
  const int blockM = blockIdx.y * 128;

  intx4 acc[4][4];
#pragma unroll
  for (int i = 0; i < 4; ++i)
#pragma unroll
    for (int j = 0; j < 4; ++j) acc[i][j] = (intx4)0;

  const char* Abase = (const char*)(A + (size_t)blockM * K_DIM);
  const char* Bbase = (const char*)(B + (size_t)blockN * K_DIM);

  // staging: 512 chunks per matrix, 2 per thread
  const int c0 = tid, c1 = 256 + tid;
  const int r0 = c0 >> 2, kc0 = (c0 & 3) ^ ((c0 >> 3) & 3);
  const int r1 = c1 >> 2, kc1 = (c1 & 3) ^ ((c1 >> 3) & 3);

  for (int kt = 0; kt < K_DIM / 64; ++kt) {
    const size_t koff = (size_t)kt * 64;
    gload_lds16(Abase + (size_t)r0 * K_DIM + koff + kc0 * 16, &As[c0 * 16]);
    gload_lds16(Abase + (size_t)r1 * K_DIM + koff + kc1 * 16, &As[c1 * 16]);
    gload_lds16(Bbase + (size_t)r0 * K_DIM + koff + kc0 * 16, &Bs[c0 * 16]);
    gload_lds16(Bbase + (size_t)r1 * K_DIM + koff + kc1 * 16, &Bs[c1 * 16]);
    __syncthreads();

    intx4 af[4], bfr[4];
#pragma unroll
    for (int mi = 0; mi < 4; ++mi)
      af[mi] = *(const intx4*)&As[(wm * 64 + mi * 16 + lr) * 64 + qs * 16];
#pragma unroll
    for (int ni = 0; ni < 4; ++ni)
      bfr[ni] = *(const intx4*)&Bs[(wn * 64 + ni * 16 + lr) * 64 + qs * 16];
#pragma unroll
    for (int mi = 0; mi < 4; ++mi)
#pragma unroll
      for (int ni = 0; ni < 4; ++ni)
        acc[mi][ni] = __builtin_amdgcn_mfma_i32_16x16x64_i8(
            af[mi], bfr[ni], acc[mi][ni], 0, 0, 0);
    __syncthreads();
  }

  // epilogue: C/D layout col = lane&15, row = quad*4 + reg (dtype-independent)
#pragma unroll
  for (int ni = 0; ni < 4; ++ni) {
    const int col = blockN + wn * 64 + ni * 16 + lr;
    const float swv = sw[col];
    const float bv = bias[col];
#pragma unroll
    for (int mi = 0; mi < 4; ++mi) {
      const int row0 = blockM + wm * 64 + mi * 16 + q * 4;
#pragma unroll
      for (int r = 0; r < 4; ++r) {
        const float s = sx[row0 + r] * swv;
        out[(size_t)(row0 + r) * N_DIM + col] = (float)acc[mi][ni][r] * s + bv;
      }
    }
  }
}

extern "C" void kernel_launch(void* const* d_in, const int* in_sizes, int n_in,
                              void* d_out, int out_size, void* d_ws, size_t ws_size,
                              hipStream_t stream) {
  const float* x      = (const float*)d_in[0];
  const float* cs     = (const float*)d_in[1];
  const u32*   qw     = (const u32*)d_in[2];
  const int*   perm   = (const int*)d_in[3];
  const float* scales = (const float*)d_in[4];
  const float* zeros  = (const float*)d_in[5];
  const float* bias   = (const float*)d_in[6];
  float* out = (float*)d_out;

  u8* xq = (u8*)d_ws;                               // 32 MiB: M*K i8
  u8* wq = xq + (size_t)M_DIM * K_DIM;              // 16 MiB: N*K i8 (permuted)
  float* sx = (float*)(wq + (size_t)N_DIM * K_DIM); // 32 KiB
  float* sw = sx + M_DIM;                           // 16 KiB

  hipLaunchKernelGGL(prep_x, dim3(M_DIM), dim3(256), 0, stream, x, cs, xq, sx);
  hipLaunchKernelGGL(prep_w, dim3(N_DIM), dim3(256), 0, stream,
                     qw, perm, scales, zeros, wq, sw);
  hipLaunchKernelGGL(gemm_i8, dim3(N_DIM / 128, M_DIM / 128), dim3(256), 0,
                     stream, xq, wq, sx, sw, bias, out);
}